// Round 9
// baseline (396.644 us; speedup 1.0000x reference)
//
#include <hip/hip_runtime.h>
#include <hip/hip_bf16.h>

// ---------------------------------------------------------------------------
// GraphChebNet: 3-layer ChebConv (K=2), N=50000, E=400000.
// Round 9: (1) far-atomic-free CSR build. Round-8 counters: prep=46us at
// VALUBusy 1.7% / HBM 1.1TB/s -> 800K device-scope atomics are throughput-
// bound at the fabric; fill adds 400K more. Replaced by LDS-privatized
// counting sort: 16 edge-chunks x 7 bin-ranges (8192 bins = 32KB LDS),
// hist (dst for CSR, src for deg) -> reduce+scan -> per-chunk bases HS ->
// fill with LDS-rank. Only LDS atomics; all cross-kernel edges plain->plain
// (proven pattern). No memsets needed. (2) GEMM 32x256 tiles -> 1563 blocks
// (round-8 64x256 = 782 blocks = grid-starved at 22% occupancy).
// ---------------------------------------------------------------------------

typedef __attribute__((ext_vector_type(8))) short bf16x8;
typedef __attribute__((ext_vector_type(4))) float f32x4;

#define NCH 16        // edge chunks
#define RBITS 13
#define RBINS 8192    // bins per range (32KB LDS as int)

__device__ __forceinline__ float bf2f(unsigned int lo16) {
    unsigned int t = lo16 << 16;
    return __builtin_bit_cast(float, t);
}
__device__ __forceinline__ unsigned short f2bf(float f) {
    unsigned int u = __builtin_bit_cast(unsigned int, f);
    unsigned int r = (u + 0x7fffu + ((u >> 16) & 1u)) >> 16;   // RNE
    return (unsigned short)r;
}

// ---------------- prep: cast x -> bf16 + 6 weight transposes ----------------
struct PrepParams {
    const float* x;
    unsigned short* xb;
    int gC;
    const float* W[6];
    unsigned short* WT[6];
    int K[6];
};

__global__ __launch_bounds__(256) void prep2_kernel(PrepParams p) {
    __shared__ float t[32][33];
    int b = blockIdx.x;
    int tid = threadIdx.x;
    if (b < p.gC) {
        long long i = (long long)b * 256 + tid;   // exact: gC*256 elements
        float4 v = reinterpret_cast<const float4*>(p.x)[i];
        ushort4 o;
        o.x = f2bf(v.x); o.y = f2bf(v.y); o.z = f2bf(v.z); o.w = f2bf(v.w);
        reinterpret_cast<ushort4*>(p.xb)[i] = o;
        return;
    }
    b -= p.gC;                       // 0..383 : 6 matrices x 64 tiles
    int m = b >> 6;
    int rem = b & 63;
    int K = p.K[m];
    int kb = (rem & 7) * 32, nb = (rem >> 3) * 32;
    if (kb >= K) return;
    const float* W = p.W[m];
    unsigned short* WT = p.WT[m];
    int lx = tid & 31, ly = tid >> 5;   // 32 x 8
    #pragma unroll
    for (int i = 0; i < 32; i += 8)
        t[ly + i][lx] = W[(size_t)(kb + ly + i) * 256 + nb + lx];
    __syncthreads();
    #pragma unroll
    for (int i = 0; i < 32; i += 8)
        WT[(size_t)(nb + ly + i) * K + kb + lx] = f2bf(t[lx][ly + i]);
}

// ---------------- hist: per-(chunk,range) histograms, LDS atomics only ------
// blocks [0, NCH*NR)        : dst histogram -> H   (CSR counts)
// blocks [NCH*NR, 2*NCH*NR) : src histogram -> H2  (deg, excl self-loops)
__global__ __launch_bounds__(256) void hist_kernel(const int* __restrict__ src,
                                                   const int* __restrict__ dst,
                                                   int* __restrict__ H,
                                                   int* __restrict__ H2,
                                                   int E, int NR, int NPAD) {
    __shared__ int h[RBINS];
    int tid = threadIdx.x;
    int b = blockIdx.x;
    int srcpass = (b >= NCH * NR);
    if (srcpass) b -= NCH * NR;
    int c = b / NR, r = b % NR;
    int r0 = r << RBITS;
    for (int i = tid; i < RBINS; i += 256) h[i] = 0;
    __syncthreads();
    int EC = (E + NCH - 1) / NCH;
    int e0 = c * EC, e1 = min(e0 + EC, E);
    if (!srcpass) {
        for (int e = e0 + tid; e < e1; e += 256) {
            int d = dst[e] - r0;
            if ((unsigned)d < RBINS) atomicAdd(&h[d], 1);
        }
    } else {
        for (int e = e0 + tid; e < e1; e += 256) {
            int s = src[e];
            int d = s - r0;
            if ((unsigned)d < RBINS && s != dst[e]) atomicAdd(&h[d], 1);
        }
    }
    __syncthreads();
    int* out = (srcpass ? H2 : H) + (size_t)c * NPAD + r0;
    for (int i = tid; i < RBINS; i += 256) out[i] = h[i];
}

// ---------------- reduce H/H2 -> cnt, dinv, scan partials ----------------
__global__ __launch_bounds__(256) void reduce_scan_partial(const int* __restrict__ H,
                                                           const int* __restrict__ H2,
                                                           int* __restrict__ cnt,
                                                           float* __restrict__ dinv,
                                                           int* __restrict__ part,
                                                           int N, int NPAD) {
    __shared__ int lds[256];
    int tid = threadIdx.x;
    int base = blockIdx.x * 1024 + tid * 4;
    int s = 0;
    #pragma unroll
    for (int i = 0; i < 4; ++i) {
        int d = base + i;
        if (d < N) {
            int cn = 0, dg = 0;
            for (int c = 0; c < NCH; ++c) {
                cn += H[(size_t)c * NPAD + d];
                dg += H2[(size_t)c * NPAD + d];
            }
            cnt[d] = cn;
            dinv[d] = (dg > 0) ? rsqrtf((float)dg) : 0.0f;
            s += cn;
        }
    }
    lds[tid] = s;
    __syncthreads();
    for (int off = 128; off > 0; off >>= 1) {
        if (tid < off) lds[tid] += lds[tid + off];
        __syncthreads();
    }
    if (tid == 0) part[blockIdx.x] = lds[0];
}

// wave-parallel exclusive scan of part[NB] (NB <= 64)
__global__ __launch_bounds__(64) void scan_small(int* __restrict__ part, int NB,
                                                 int* __restrict__ rowptr, int N) {
    int lane = threadIdx.x;
    int v = (lane < NB) ? part[lane] : 0;
    int inc = v;
    #pragma unroll
    for (int off = 1; off < 64; off <<= 1) {
        int t = __shfl_up(inc, off, 64);
        if (lane >= off) inc += t;
    }
    if (lane < NB) part[lane] = inc - v;   // exclusive
    if (lane == 63) rowptr[N] = inc;       // total
}

// rowptr (exclusive prefix of cnt) + per-chunk bases HS[c][d]
__global__ __launch_bounds__(256) void scan_chunk_base(const int* __restrict__ cnt,
                                                       const int* __restrict__ part,
                                                       const int* __restrict__ H,
                                                       int* __restrict__ rowptr,
                                                       int* __restrict__ HS,
                                                       int N, int NPAD) {
    __shared__ int lds[256];
    int tid = threadIdx.x;
    int base = blockIdx.x * 1024 + tid * 4;
    int c4[4];
    #pragma unroll
    for (int i = 0; i < 4; ++i) c4[i] = (base + i < N) ? cnt[base + i] : 0;
    int ts = c4[0] + c4[1] + c4[2] + c4[3];
    lds[tid] = ts;
    __syncthreads();
    for (int off = 1; off < 256; off <<= 1) {
        int v = (tid >= off) ? lds[tid - off] : 0;
        __syncthreads();
        lds[tid] += v;
        __syncthreads();
    }
    int o = part[blockIdx.x] + lds[tid] - ts;
    #pragma unroll
    for (int i = 0; i < 4; ++i) {
        int d = base + i;
        if (d < N) {
            rowptr[d] = o;
            int run = o;
            for (int c = 0; c < NCH; ++c) {
                HS[(size_t)c * NPAD + d] = run;
                run += H[(size_t)c * NPAD + d];
            }
            o = run;
        }
    }
}

// ---------------- fill: place edges via LDS ranks (no global atomics) -------
__global__ __launch_bounds__(256) void fill_kernel(const int* __restrict__ src,
                                                   const int* __restrict__ dst,
                                                   const float* __restrict__ dinv,
                                                   const int* __restrict__ HS,
                                                   int* __restrict__ esrc,
                                                   float* __restrict__ ew,
                                                   int E, int NR, int NPAD) {
    __shared__ int h[RBINS];
    int tid = threadIdx.x;
    int b = blockIdx.x;
    int c = b / NR, r = b % NR;
    int r0 = r << RBITS;
    for (int i = tid; i < RBINS; i += 256) h[i] = 0;
    __syncthreads();
    int EC = (E + NCH - 1) / NCH;
    int e0 = c * EC, e1 = min(e0 + EC, E);
    for (int e = e0 + tid; e < e1; e += 256) {
        int d = dst[e];
        int dl = d - r0;
        if ((unsigned)dl < RBINS) {
            int s = src[e];
            int rank = atomicAdd(&h[dl], 1);
            int pos = HS[(size_t)c * NPAD + d] + rank;
            esrc[pos] = s;
            ew[pos] = (s != d) ? (-dinv[s] * dinv[d]) : 0.0f;
        }
    }
}

// ---------------- gather: tx[n,:] = sum_e w_e * x[src_e,:] ----------------
template <int V> struct RowT;
template <> struct RowT<4> { using T = uint2; };
template <> struct RowT<8> { using T = uint4; };

__device__ __forceinline__ void fma_row(float* acc, uint2 u, float wv) {
    acc[0] += wv * bf2f(u.x & 0xffffu);
    acc[1] += wv * bf2f(u.x >> 16);
    acc[2] += wv * bf2f(u.y & 0xffffu);
    acc[3] += wv * bf2f(u.y >> 16);
}
__device__ __forceinline__ void fma_row(float* acc, uint4 u, float wv) {
    acc[0] += wv * bf2f(u.x & 0xffffu);
    acc[1] += wv * bf2f(u.x >> 16);
    acc[2] += wv * bf2f(u.y & 0xffffu);
    acc[3] += wv * bf2f(u.y >> 16);
    acc[4] += wv * bf2f(u.z & 0xffffu);
    acc[5] += wv * bf2f(u.z >> 16);
    acc[6] += wv * bf2f(u.w & 0xffffu);
    acc[7] += wv * bf2f(u.w >> 16);
}
__device__ __forceinline__ void pack_out(unsigned short* q, const float* acc, uint2*) {
    uint2 o;
    o.x = (unsigned int)f2bf(acc[0]) | ((unsigned int)f2bf(acc[1]) << 16);
    o.y = (unsigned int)f2bf(acc[2]) | ((unsigned int)f2bf(acc[3]) << 16);
    *reinterpret_cast<uint2*>(q) = o;
}
__device__ __forceinline__ void pack_out(unsigned short* q, const float* acc, uint4*) {
    uint4 o;
    o.x = (unsigned int)f2bf(acc[0]) | ((unsigned int)f2bf(acc[1]) << 16);
    o.y = (unsigned int)f2bf(acc[2]) | ((unsigned int)f2bf(acc[3]) << 16);
    o.z = (unsigned int)f2bf(acc[4]) | ((unsigned int)f2bf(acc[5]) << 16);
    o.w = (unsigned int)f2bf(acc[6]) | ((unsigned int)f2bf(acc[7]) << 16);
    *reinterpret_cast<uint4*>(q) = o;
}

template <int F>
__global__ __launch_bounds__(256) void gather_bf16(const int* __restrict__ rowptr,
                                                   const int* __restrict__ esrc,
                                                   const float* __restrict__ ew,
                                                   const unsigned short* __restrict__ xb,
                                                   unsigned short* __restrict__ txb,
                                                   int N) {
    constexpr int V = F / 32;   // 4 (F=128) or 8 (F=256)
    using T = typename RowT<V>::T;
    int half = threadIdx.x >> 5;
    int lane = threadIdx.x & 31;
    int n = blockIdx.x * 8 + half;
    if (n >= N) return;
    int beg = rowptr[n], end = rowptr[n + 1];
    float acc[V] = {};

    int k = beg;
    for (; k + 4 <= end; k += 4) {
        int s0 = esrc[k], s1 = esrc[k + 1], s2 = esrc[k + 2], s3 = esrc[k + 3];
        float w0 = ew[k], w1 = ew[k + 1], w2 = ew[k + 2], w3 = ew[k + 3];
        T r0 = *reinterpret_cast<const T*>(&xb[(size_t)s0 * F + lane * V]);
        T r1 = *reinterpret_cast<const T*>(&xb[(size_t)s1 * F + lane * V]);
        T r2 = *reinterpret_cast<const T*>(&xb[(size_t)s2 * F + lane * V]);
        T r3 = *reinterpret_cast<const T*>(&xb[(size_t)s3 * F + lane * V]);
        fma_row(acc, r0, w0);
        fma_row(acc, r1, w1);
        fma_row(acc, r2, w2);
        fma_row(acc, r3, w3);
    }
    for (; k < end; ++k) {
        int s = esrc[k];
        float wv = ew[k];
        T r = *reinterpret_cast<const T*>(&xb[(size_t)s * F + lane * V]);
        fma_row(acc, r, wv);
    }

    pack_out(&txb[(size_t)n * F + lane * V], acc, (T*)nullptr);
}

// ---------------- MFMA GEMM, 32 x 256 tiles, global_load_lds staging --------
// out[M,256] = relu?( Xb[M,K]@W0 + Tb[M,K]@W1 + b ), weights as WT[n][k] bf16.
// 1563 blocks (fixes the 782-block grid starvation of the 64-row tile).
// XOR-swizzled 16B units: LDS unit u of row R holds global unit u^(R&7).
template <int K, bool RELU, typename OutT>
__global__ __launch_bounds__(256, 4) void gemm_mfma(const unsigned short* __restrict__ Xb,
                                                    const unsigned short* __restrict__ Tb,
                                                    const unsigned short* __restrict__ W0T,
                                                    const unsigned short* __restrict__ W1T,
                                                    const float* __restrict__ bias,
                                                    OutT* __restrict__ out, int M) {
    __shared__ unsigned short As[32 * 64];
    __shared__ unsigned short Bs[256 * 64];

    const int tid = threadIdx.x;
    const int wave = tid >> 6;
    const int lane = tid & 63;
    const int l15 = lane & 15;
    const int quad = lane >> 4;
    const int row0 = blockIdx.x * 32;
    const int swz = ((lane & 7) ^ ((lane >> 3) & 7)) * 8;   // shorts

    f32x4 acc[2][4];
    #pragma unroll
    for (int i = 0; i < 2; ++i)
        #pragma unroll
        for (int j = 0; j < 4; ++j) acc[i][j] = (f32x4){0.f, 0.f, 0.f, 0.f};

    typedef const __attribute__((address_space(1))) void gvoid;
    typedef __attribute__((address_space(3))) void lvoid;

    #pragma unroll
    for (int pass = 0; pass < 2; ++pass) {
        const unsigned short* Amat = pass ? Tb : Xb;
        const unsigned short* Wmat = pass ? W1T : W0T;
        for (int k0 = 0; k0 < K; k0 += 64) {
            if (pass != 0 || k0 != 0) __syncthreads();
            {
                int grow = row0 + wave * 8 + (lane >> 3);
                if (grow > M - 1) grow = M - 1;
                const unsigned short* gp = &Amat[(size_t)grow * K + k0 + swz];
                __builtin_amdgcn_global_load_lds((gvoid*)gp,
                    (lvoid*)&As[(wave * 8) * 64], 16, 0, 0);
            }
            #pragma unroll
            for (int r = 0; r < 8; ++r) {
                int brow = r * 32 + wave * 8 + (lane >> 3);
                const unsigned short* gp = &Wmat[(size_t)brow * K + k0 + swz];
                __builtin_amdgcn_global_load_lds((gvoid*)gp,
                    (lvoid*)&Bs[(r * 32 + wave * 8) * 64], 16, 0, 0);
            }
            __syncthreads();

            #pragma unroll
            for (int kf = 0; kf < 2; ++kf) {
                const int col = (((kf * 4 + quad) ^ (l15 & 7)) * 8);
                bf16x8 a[2], b[4];
                #pragma unroll
                for (int mt = 0; mt < 2; ++mt)
                    a[mt] = *reinterpret_cast<const bf16x8*>(&As[(mt * 16 + l15) * 64 + col]);
                #pragma unroll
                for (int nt = 0; nt < 4; ++nt)
                    b[nt] = *reinterpret_cast<const bf16x8*>(
                        &Bs[(wave * 64 + nt * 16 + l15) * 64 + col]);
                #pragma unroll
                for (int mt = 0; mt < 2; ++mt)
                    #pragma unroll
                    for (int nt = 0; nt < 4; ++nt)
                        acc[mt][nt] = __builtin_amdgcn_mfma_f32_16x16x32_bf16(
                            a[mt], b[nt], acc[mt][nt], 0, 0, 0);
            }
        }
    }

    // epilogue: C/D layout col=lane&15, row=quad*4+reg
    #pragma unroll
    for (int mt = 0; mt < 2; ++mt) {
        #pragma unroll
        for (int r = 0; r < 4; ++r) {
            int m = row0 + mt * 16 + quad * 4 + r;
            if (m >= M) continue;
            #pragma unroll
            for (int nt = 0; nt < 4; ++nt) {
                int n = wave * 64 + nt * 16 + l15;
                float v = acc[mt][nt][r] + bias[n];
                if (RELU) v = fmaxf(v, 0.0f);
                if constexpr (sizeof(OutT) == 2)
                    out[(size_t)m * 256 + n] = (OutT)f2bf(v);
                else
                    out[(size_t)m * 256 + n] = (OutT)v;
            }
        }
    }
}

static inline size_t align_up(size_t v, size_t a) { return (v + a - 1) / a * a; }

extern "C" void kernel_launch(void* const* d_in, const int* in_sizes, int n_in,
                              void* d_out, int out_size, void* d_ws, size_t ws_size,
                              hipStream_t stream) {
    const float* x    = (const float*)d_in[0];
    const int*   ei   = (const int*)d_in[1];
    const float* W1_0 = (const float*)d_in[2];
    const float* W1_1 = (const float*)d_in[3];
    const float* b1   = (const float*)d_in[4];
    const float* W2_0 = (const float*)d_in[5];
    const float* W2_1 = (const float*)d_in[6];
    const float* b2   = (const float*)d_in[7];
    const float* W3_0 = (const float*)d_in[8];
    const float* W3_1 = (const float*)d_in[9];
    const float* b3   = (const float*)d_in[10];
    float* out = (float*)d_out;

    const int N = in_sizes[0] / 128;
    const int E = in_sizes[1] / 2;
    const int* src = ei;
    const int* dst = ei + E;

    const int NR = (N + RBINS - 1) / RBINS;     // 7 for N=50000
    const int NPAD = NR * RBINS;                // 57344

    typedef unsigned short u16;
    char* ws = (char*)d_ws;
    size_t off = 0;
    float* dinv   = (float*)(ws + off); off = align_up(off + (size_t)N * 4, 256);
    int*   cnt    = (int*)  (ws + off); off = align_up(off + (size_t)N * 4, 256);
    int*   rowptr = (int*)  (ws + off); off = align_up(off + (size_t)(N + 1) * 4, 256);
    int*   part   = (int*)  (ws + off); off = align_up(off + 256 * 4, 256);
    int*   H      = (int*)  (ws + off); off = align_up(off + (size_t)NCH * NPAD * 4, 256);
    int*   H2     = (int*)  (ws + off); off = align_up(off + (size_t)NCH * NPAD * 4, 256);
    int*   HS     = (int*)  (ws + off); off = align_up(off + (size_t)NCH * NPAD * 4, 256);
    int*   esrc   = (int*)  (ws + off); off = align_up(off + (size_t)E * 4, 256);
    float* ew     = (float*)(ws + off); off = align_up(off + (size_t)E * 4, 256);
    u16*   xb     = (u16*)  (ws + off); off = align_up(off + (size_t)N * 128 * 2, 256);
    u16*   txb    = (u16*)  (ws + off); off = align_up(off + (size_t)N * 256 * 2, 256);
    u16*   h1b    = (u16*)  (ws + off); off = align_up(off + (size_t)N * 256 * 2, 256);
    u16*   h2b    = (u16*)  (ws + off); off = align_up(off + (size_t)N * 256 * 2, 256);
    u16*   W10T   = (u16*)  (ws + off); off = align_up(off + (size_t)256 * 128 * 2, 256);
    u16*   W11T   = (u16*)  (ws + off); off = align_up(off + (size_t)256 * 128 * 2, 256);
    u16*   W20T   = (u16*)  (ws + off); off = align_up(off + (size_t)256 * 256 * 2, 256);
    u16*   W21T   = (u16*)  (ws + off); off = align_up(off + (size_t)256 * 256 * 2, 256);
    u16*   W30T   = (u16*)  (ws + off); off = align_up(off + (size_t)256 * 256 * 2, 256);
    u16*   W31T   = (u16*)  (ws + off); off = align_up(off + (size_t)256 * 256 * 2, 256);
    (void)ws_size;

    const int TB = 256;
    const int gC = (int)(((long long)N * 128 / 4) / 256);   // 6250 (exact)
    const int NB = (N + 1023) / 1024;                       // 49

    // ---- prep: cast x + transpose weights (no atomics anywhere) ----
    {
        PrepParams p;
        p.x = x; p.xb = xb; p.gC = gC;
        p.W[0] = W1_0; p.WT[0] = W10T; p.K[0] = 128;
        p.W[1] = W1_1; p.WT[1] = W11T; p.K[1] = 128;
        p.W[2] = W2_0; p.WT[2] = W20T; p.K[2] = 256;
        p.W[3] = W2_1; p.WT[3] = W21T; p.K[3] = 256;
        p.W[4] = W3_0; p.WT[4] = W30T; p.K[4] = 256;
        p.W[5] = W3_1; p.WT[5] = W31T; p.K[5] = 256;
        prep2_kernel<<<gC + 384, TB, 0, stream>>>(p);
    }

    // ---- CSR build: LDS counting sort ----
    hist_kernel<<<2 * NCH * NR, TB, 0, stream>>>(src, dst, H, H2, E, NR, NPAD);
    reduce_scan_partial<<<NB, TB, 0, stream>>>(H, H2, cnt, dinv, part, N, NPAD);
    scan_small<<<1, 64, 0, stream>>>(part, NB, rowptr, N);
    scan_chunk_base<<<NB, TB, 0, stream>>>(cnt, part, H, rowptr, HS, N, NPAD);
    fill_kernel<<<NCH * NR, TB, 0, stream>>>(src, dst, dinv, HS, esrc, ew, E, NR, NPAD);

    dim3 gemmGrid((N + 31) / 32);
    dim3 gatherGrid((N + 7) / 8);

    // ---- layer 1: F=128 ----
    gather_bf16<128><<<gatherGrid, TB, 0, stream>>>(rowptr, esrc, ew, xb, txb, N);
    gemm_mfma<128, true, u16><<<gemmGrid, TB, 0, stream>>>(xb, txb, W10T, W11T, b1, h1b, N);

    // ---- layer 2: F=256 ----
    gather_bf16<256><<<gatherGrid, TB, 0, stream>>>(rowptr, esrc, ew, h1b, txb, N);
    gemm_mfma<256, true, u16><<<gemmGrid, TB, 0, stream>>>(h1b, txb, W20T, W21T, b2, h2b, N);

    // ---- layer 3: F=256, no relu, fp32 out ----
    gather_bf16<256><<<gatherGrid, TB, 0, stream>>>(rowptr, esrc, ew, h2b, txb, N);
    gemm_mfma<256, false, float><<<gemmGrid, TB, 0, stream>>>(h2b, txb, W30T, W31T, b3, out, N);
}

// Round 10
// 364.365 us; speedup vs baseline: 1.0886x; 1.0886x over previous
//
#include <hip/hip_runtime.h>
#include <hip/hip_bf16.h>

// ---------------------------------------------------------------------------
// GraphChebNet: 3-layer ChebConv (K=2), N=50000, E=400000.
// Round 10: fix round-9's grid starvation (fill had 112 blocks = 0.44/CU,
// 76us at 4% occupancy). NCH 16->64: fill=448 blocks, hist=896. Cast+
// transpose fused into the hist launch (atomic-free prep, one kernel, hist
// blocks first). ew[] eliminated: w = -dinv[s]*dinv[d] factorizes -> gather
// accumulates dinv[s]*x[s] and scales by -dinv[n] at the end; CSR stores
// esrc only (non-self edges). Zero far atomics, zero memsets, 11 dispatches.
// GEMM: 32x256 tiles (1563 blocks) from round 9.
// ---------------------------------------------------------------------------

typedef __attribute__((ext_vector_type(8))) short bf16x8;
typedef __attribute__((ext_vector_type(4))) float f32x4;

#define NCH 64        // edge chunks
#define RBITS 13
#define RBINS 8192    // bins per range (32KB LDS as int)

__device__ __forceinline__ float bf2f(unsigned int lo16) {
    unsigned int t = lo16 << 16;
    return __builtin_bit_cast(float, t);
}
__device__ __forceinline__ unsigned short f2bf(float f) {
    unsigned int u = __builtin_bit_cast(unsigned int, f);
    unsigned int r = (u + 0x7fffu + ((u >> 16) & 1u)) >> 16;   // RNE
    return (unsigned short)r;
}

// ---------------- fused hist + prep ----------------
// blocks [0, G)        : dst histogram (s!=d) -> H   (CSR counts)
// blocks [G, 2G)       : src histogram (s!=d) -> H2  (deg)
// blocks [2G, 2G+gC)   : cast x -> bf16
// blocks [2G+gC, +384) : 6 weight transposes
struct HPParams {
    const int* src;
    const int* dst;
    int* H;
    int* H2;
    int E, NR, NPAD;
    const float* x;
    unsigned short* xb;
    int gC;
    const float* W[6];
    unsigned short* WT[6];
    int K[6];
};

__global__ __launch_bounds__(256) void hist_prep_kernel(HPParams p) {
    __shared__ int h[RBINS];
    int b = blockIdx.x;
    int tid = threadIdx.x;
    const int G = NCH * p.NR;

    if (b < 2 * G) {
        int srcpass = (b >= G);
        if (srcpass) b -= G;
        int c = b / p.NR, r = b % p.NR;
        int r0 = r << RBITS;
        for (int i = tid; i < RBINS; i += 256) h[i] = 0;
        __syncthreads();
        int EC = (p.E + NCH - 1) / NCH;
        int e0 = c * EC, e1 = min(e0 + EC, p.E);
        if (!srcpass) {
            for (int e = e0 + tid; e < e1; e += 256) {
                int d = p.dst[e];
                int dl = d - r0;
                if ((unsigned)dl < RBINS && p.src[e] != d) atomicAdd(&h[dl], 1);
            }
        } else {
            for (int e = e0 + tid; e < e1; e += 256) {
                int s = p.src[e];
                int sl = s - r0;
                if ((unsigned)sl < RBINS && s != p.dst[e]) atomicAdd(&h[sl], 1);
            }
        }
        __syncthreads();
        int* out = (srcpass ? p.H2 : p.H) + (size_t)c * p.NPAD + r0;
        for (int i = tid; i < RBINS; i += 256) out[i] = h[i];
        return;
    }
    b -= 2 * G;
    if (b < p.gC) {
        long long i = (long long)b * 256 + tid;   // exact: gC*256 elements
        float4 v = reinterpret_cast<const float4*>(p.x)[i];
        ushort4 o;
        o.x = f2bf(v.x); o.y = f2bf(v.y); o.z = f2bf(v.z); o.w = f2bf(v.w);
        reinterpret_cast<ushort4*>(p.xb)[i] = o;
        return;
    }
    b -= p.gC;                       // 0..383 : 6 matrices x 64 tiles
    float (*t)[33] = reinterpret_cast<float(*)[33]>(h);
    int m = b >> 6;
    int rem = b & 63;
    int K = p.K[m];
    int kb = (rem & 7) * 32, nb = (rem >> 3) * 32;
    if (kb >= K) return;
    const float* W = p.W[m];
    unsigned short* WT = p.WT[m];
    int lx = tid & 31, ly = tid >> 5;   // 32 x 8
    #pragma unroll
    for (int i = 0; i < 32; i += 8)
        t[ly + i][lx] = W[(size_t)(kb + ly + i) * 256 + nb + lx];
    __syncthreads();
    #pragma unroll
    for (int i = 0; i < 32; i += 8)
        WT[(size_t)(nb + ly + i) * K + kb + lx] = f2bf(t[lx][ly + i]);
}

// ---------------- reduce H/H2 -> cnt, dinv, scan partials ----------------
__global__ __launch_bounds__(256) void reduce_scan_partial(const int* __restrict__ H,
                                                           const int* __restrict__ H2,
                                                           int* __restrict__ cnt,
                                                           float* __restrict__ dinv,
                                                           int* __restrict__ part,
                                                           int N, int NPAD) {
    __shared__ int lds[256];
    int tid = threadIdx.x;
    int base = blockIdx.x * 1024 + tid * 4;
    int s = 0;
    #pragma unroll
    for (int i = 0; i < 4; ++i) {
        int d = base + i;
        if (d < N) {
            int cn = 0, dg = 0;
            for (int c = 0; c < NCH; ++c) {
                cn += H[(size_t)c * NPAD + d];
                dg += H2[(size_t)c * NPAD + d];
            }
            cnt[d] = cn;
            dinv[d] = (dg > 0) ? rsqrtf((float)dg) : 0.0f;
            s += cn;
        }
    }
    lds[tid] = s;
    __syncthreads();
    for (int off = 128; off > 0; off >>= 1) {
        if (tid < off) lds[tid] += lds[tid + off];
        __syncthreads();
    }
    if (tid == 0) part[blockIdx.x] = lds[0];
}

// wave-parallel exclusive scan of part[NB] (NB <= 64)
__global__ __launch_bounds__(64) void scan_small(int* __restrict__ part, int NB,
                                                 int* __restrict__ rowptr, int N) {
    int lane = threadIdx.x;
    int v = (lane < NB) ? part[lane] : 0;
    int inc = v;
    #pragma unroll
    for (int off = 1; off < 64; off <<= 1) {
        int t = __shfl_up(inc, off, 64);
        if (lane >= off) inc += t;
    }
    if (lane < NB) part[lane] = inc - v;   // exclusive
    if (lane == 63) rowptr[N] = inc;       // total
}

// rowptr (exclusive prefix of cnt) + per-chunk bases HS[c][d]
__global__ __launch_bounds__(256) void scan_chunk_base(const int* __restrict__ cnt,
                                                       const int* __restrict__ part,
                                                       const int* __restrict__ H,
                                                       int* __restrict__ rowptr,
                                                       int* __restrict__ HS,
                                                       int N, int NPAD) {
    __shared__ int lds[256];
    int tid = threadIdx.x;
    int base = blockIdx.x * 1024 + tid * 4;
    int c4[4];
    #pragma unroll
    for (int i = 0; i < 4; ++i) c4[i] = (base + i < N) ? cnt[base + i] : 0;
    int ts = c4[0] + c4[1] + c4[2] + c4[3];
    lds[tid] = ts;
    __syncthreads();
    for (int off = 1; off < 256; off <<= 1) {
        int v = (tid >= off) ? lds[tid - off] : 0;
        __syncthreads();
        lds[tid] += v;
        __syncthreads();
    }
    int o = part[blockIdx.x] + lds[tid] - ts;
    #pragma unroll
    for (int i = 0; i < 4; ++i) {
        int d = base + i;
        if (d < N) {
            rowptr[d] = o;
            int run = o;
            for (int c = 0; c < NCH; ++c) {
                HS[(size_t)c * NPAD + d] = run;
                run += H[(size_t)c * NPAD + d];
            }
            o = run;
        }
    }
}

// ---------------- fill: place non-self edges via LDS ranks ----------------
__global__ __launch_bounds__(256) void fill_kernel(const int* __restrict__ src,
                                                   const int* __restrict__ dst,
                                                   const int* __restrict__ HS,
                                                   int* __restrict__ esrc,
                                                   int E, int NR, int NPAD) {
    __shared__ int h[RBINS];
    int tid = threadIdx.x;
    int b = blockIdx.x;
    int c = b / NR, r = b % NR;
    int r0 = r << RBITS;
    for (int i = tid; i < RBINS; i += 256) h[i] = 0;
    __syncthreads();
    int EC = (E + NCH - 1) / NCH;
    int e0 = c * EC, e1 = min(e0 + EC, E);
    for (int e = e0 + tid; e < e1; e += 256) {
        int d = dst[e];
        int dl = d - r0;
        if ((unsigned)dl < RBINS) {
            int s = src[e];
            if (s != d) {
                int rank = atomicAdd(&h[dl], 1);
                esrc[HS[(size_t)c * NPAD + d] + rank] = s;
            }
        }
    }
}

// ---------------- gather: tx[n,:] = -dinv[n] * sum_e dinv[s]*x[s,:] --------
template <int V> struct RowT;
template <> struct RowT<4> { using T = uint2; };
template <> struct RowT<8> { using T = uint4; };

__device__ __forceinline__ void fma_row(float* acc, uint2 u, float wv) {
    acc[0] += wv * bf2f(u.x & 0xffffu);
    acc[1] += wv * bf2f(u.x >> 16);
    acc[2] += wv * bf2f(u.y & 0xffffu);
    acc[3] += wv * bf2f(u.y >> 16);
}
__device__ __forceinline__ void fma_row(float* acc, uint4 u, float wv) {
    acc[0] += wv * bf2f(u.x & 0xffffu);
    acc[1] += wv * bf2f(u.x >> 16);
    acc[2] += wv * bf2f(u.y & 0xffffu);
    acc[3] += wv * bf2f(u.y >> 16);
    acc[4] += wv * bf2f(u.z & 0xffffu);
    acc[5] += wv * bf2f(u.z >> 16);
    acc[6] += wv * bf2f(u.w & 0xffffu);
    acc[7] += wv * bf2f(u.w >> 16);
}
__device__ __forceinline__ void pack_out(unsigned short* q, const float* acc, uint2*) {
    uint2 o;
    o.x = (unsigned int)f2bf(acc[0]) | ((unsigned int)f2bf(acc[1]) << 16);
    o.y = (unsigned int)f2bf(acc[2]) | ((unsigned int)f2bf(acc[3]) << 16);
    *reinterpret_cast<uint2*>(q) = o;
}
__device__ __forceinline__ void pack_out(unsigned short* q, const float* acc, uint4*) {
    uint4 o;
    o.x = (unsigned int)f2bf(acc[0]) | ((unsigned int)f2bf(acc[1]) << 16);
    o.y = (unsigned int)f2bf(acc[2]) | ((unsigned int)f2bf(acc[3]) << 16);
    o.z = (unsigned int)f2bf(acc[4]) | ((unsigned int)f2bf(acc[5]) << 16);
    o.w = (unsigned int)f2bf(acc[6]) | ((unsigned int)f2bf(acc[7]) << 16);
    *reinterpret_cast<uint4*>(q) = o;
}

template <int F>
__global__ __launch_bounds__(256) void gather_bf16(const int* __restrict__ rowptr,
                                                   const int* __restrict__ esrc,
                                                   const float* __restrict__ dinv,
                                                   const unsigned short* __restrict__ xb,
                                                   unsigned short* __restrict__ txb,
                                                   int N) {
    constexpr int V = F / 32;   // 4 (F=128) or 8 (F=256)
    using T = typename RowT<V>::T;
    int half = threadIdx.x >> 5;
    int lane = threadIdx.x & 31;
    int n = blockIdx.x * 8 + half;
    if (n >= N) return;
    int beg = rowptr[n], end = rowptr[n + 1];
    float acc[V] = {};

    int k = beg;
    for (; k + 4 <= end; k += 4) {
        int s0 = esrc[k], s1 = esrc[k + 1], s2 = esrc[k + 2], s3 = esrc[k + 3];
        float w0 = dinv[s0], w1 = dinv[s1], w2 = dinv[s2], w3 = dinv[s3];
        T r0 = *reinterpret_cast<const T*>(&xb[(size_t)s0 * F + lane * V]);
        T r1 = *reinterpret_cast<const T*>(&xb[(size_t)s1 * F + lane * V]);
        T r2 = *reinterpret_cast<const T*>(&xb[(size_t)s2 * F + lane * V]);
        T r3 = *reinterpret_cast<const T*>(&xb[(size_t)s3 * F + lane * V]);
        fma_row(acc, r0, w0);
        fma_row(acc, r1, w1);
        fma_row(acc, r2, w2);
        fma_row(acc, r3, w3);
    }
    for (; k < end; ++k) {
        int s = esrc[k];
        float wv = dinv[s];
        T r = *reinterpret_cast<const T*>(&xb[(size_t)s * F + lane * V]);
        fma_row(acc, r, wv);
    }

    float sc = -dinv[n];
    #pragma unroll
    for (int i = 0; i < V; ++i) acc[i] *= sc;

    pack_out(&txb[(size_t)n * F + lane * V], acc, (T*)nullptr);
}

// ---------------- MFMA GEMM, 32 x 256 tiles, global_load_lds staging --------
template <int K, bool RELU, typename OutT>
__global__ __launch_bounds__(256, 4) void gemm_mfma(const unsigned short* __restrict__ Xb,
                                                    const unsigned short* __restrict__ Tb,
                                                    const unsigned short* __restrict__ W0T,
                                                    const unsigned short* __restrict__ W1T,
                                                    const float* __restrict__ bias,
                                                    OutT* __restrict__ out, int M) {
    __shared__ unsigned short As[32 * 64];
    __shared__ unsigned short Bs[256 * 64];

    const int tid = threadIdx.x;
    const int wave = tid >> 6;
    const int lane = tid & 63;
    const int l15 = lane & 15;
    const int quad = lane >> 4;
    const int row0 = blockIdx.x * 32;
    const int swz = ((lane & 7) ^ ((lane >> 3) & 7)) * 8;   // shorts

    f32x4 acc[2][4];
    #pragma unroll
    for (int i = 0; i < 2; ++i)
        #pragma unroll
        for (int j = 0; j < 4; ++j) acc[i][j] = (f32x4){0.f, 0.f, 0.f, 0.f};

    typedef const __attribute__((address_space(1))) void gvoid;
    typedef __attribute__((address_space(3))) void lvoid;

    #pragma unroll
    for (int pass = 0; pass < 2; ++pass) {
        const unsigned short* Amat = pass ? Tb : Xb;
        const unsigned short* Wmat = pass ? W1T : W0T;
        for (int k0 = 0; k0 < K; k0 += 64) {
            if (pass != 0 || k0 != 0) __syncthreads();
            {
                int grow = row0 + wave * 8 + (lane >> 3);
                if (grow > M - 1) grow = M - 1;
                const unsigned short* gp = &Amat[(size_t)grow * K + k0 + swz];
                __builtin_amdgcn_global_load_lds((gvoid*)gp,
                    (lvoid*)&As[(wave * 8) * 64], 16, 0, 0);
            }
            #pragma unroll
            for (int r = 0; r < 8; ++r) {
                int brow = r * 32 + wave * 8 + (lane >> 3);
                const unsigned short* gp = &Wmat[(size_t)brow * K + k0 + swz];
                __builtin_amdgcn_global_load_lds((gvoid*)gp,
                    (lvoid*)&Bs[(r * 32 + wave * 8) * 64], 16, 0, 0);
            }
            __syncthreads();

            #pragma unroll
            for (int kf = 0; kf < 2; ++kf) {
                const int col = (((kf * 4 + quad) ^ (l15 & 7)) * 8);
                bf16x8 a[2], b[4];
                #pragma unroll
                for (int mt = 0; mt < 2; ++mt)
                    a[mt] = *reinterpret_cast<const bf16x8*>(&As[(mt * 16 + l15) * 64 + col]);
                #pragma unroll
                for (int nt = 0; nt < 4; ++nt)
                    b[nt] = *reinterpret_cast<const bf16x8*>(
                        &Bs[(wave * 64 + nt * 16 + l15) * 64 + col]);
                #pragma unroll
                for (int mt = 0; mt < 2; ++mt)
                    #pragma unroll
                    for (int nt = 0; nt < 4; ++nt)
                        acc[mt][nt] = __builtin_amdgcn_mfma_f32_16x16x32_bf16(
                            a[mt], b[nt], acc[mt][nt], 0, 0, 0);
            }
        }
    }

    // epilogue: C/D layout col=lane&15, row=quad*4+reg
    #pragma unroll
    for (int mt = 0; mt < 2; ++mt) {
        #pragma unroll
        for (int r = 0; r < 4; ++r) {
            int m = row0 + mt * 16 + quad * 4 + r;
            if (m >= M) continue;
            #pragma unroll
            for (int nt = 0; nt < 4; ++nt) {
                int n = wave * 64 + nt * 16 + l15;
                float v = acc[mt][nt][r] + bias[n];
                if (RELU) v = fmaxf(v, 0.0f);
                if constexpr (sizeof(OutT) == 2)
                    out[(size_t)m * 256 + n] = (OutT)f2bf(v);
                else
                    out[(size_t)m * 256 + n] = (OutT)v;
            }
        }
    }
}

static inline size_t align_up(size_t v, size_t a) { return (v + a - 1) / a * a; }

extern "C" void kernel_launch(void* const* d_in, const int* in_sizes, int n_in,
                              void* d_out, int out_size, void* d_ws, size_t ws_size,
                              hipStream_t stream) {
    const float* x    = (const float*)d_in[0];
    const int*   ei   = (const int*)d_in[1];
    const float* W1_0 = (const float*)d_in[2];
    const float* W1_1 = (const float*)d_in[3];
    const float* b1   = (const float*)d_in[4];
    const float* W2_0 = (const float*)d_in[5];
    const float* W2_1 = (const float*)d_in[6];
    const float* b2   = (const float*)d_in[7];
    const float* W3_0 = (const float*)d_in[8];
    const float* W3_1 = (const float*)d_in[9];
    const float* b3   = (const float*)d_in[10];
    float* out = (float*)d_out;

    const int N = in_sizes[0] / 128;
    const int E = in_sizes[1] / 2;
    const int* src = ei;
    const int* dst = ei + E;

    const int NR = (N + RBINS - 1) / RBINS;     // 7 for N=50000
    const int NPAD = NR * RBINS;                // 57344

    typedef unsigned short u16;
    char* ws = (char*)d_ws;
    size_t off = 0;
    float* dinv   = (float*)(ws + off); off = align_up(off + (size_t)N * 4, 256);
    int*   cnt    = (int*)  (ws + off); off = align_up(off + (size_t)N * 4, 256);
    int*   rowptr = (int*)  (ws + off); off = align_up(off + (size_t)(N + 1) * 4, 256);
    int*   part   = (int*)  (ws + off); off = align_up(off + 256 * 4, 256);
    int*   H      = (int*)  (ws + off); off = align_up(off + (size_t)NCH * NPAD * 4, 256);
    int*   H2     = (int*)  (ws + off); off = align_up(off + (size_t)NCH * NPAD * 4, 256);
    int*   HS     = (int*)  (ws + off); off = align_up(off + (size_t)NCH * NPAD * 4, 256);
    int*   esrc   = (int*)  (ws + off); off = align_up(off + (size_t)E * 4, 256);
    u16*   xb     = (u16*)  (ws + off); off = align_up(off + (size_t)N * 128 * 2, 256);
    u16*   txb    = (u16*)  (ws + off); off = align_up(off + (size_t)N * 256 * 2, 256);
    u16*   h1b    = (u16*)  (ws + off); off = align_up(off + (size_t)N * 256 * 2, 256);
    u16*   h2b    = (u16*)  (ws + off); off = align_up(off + (size_t)N * 256 * 2, 256);
    u16*   W10T   = (u16*)  (ws + off); off = align_up(off + (size_t)256 * 128 * 2, 256);
    u16*   W11T   = (u16*)  (ws + off); off = align_up(off + (size_t)256 * 128 * 2, 256);
    u16*   W20T   = (u16*)  (ws + off); off = align_up(off + (size_t)256 * 256 * 2, 256);
    u16*   W21T   = (u16*)  (ws + off); off = align_up(off + (size_t)256 * 256 * 2, 256);
    u16*   W30T   = (u16*)  (ws + off); off = align_up(off + (size_t)256 * 256 * 2, 256);
    u16*   W31T   = (u16*)  (ws + off); off = align_up(off + (size_t)256 * 256 * 2, 256);
    (void)ws_size;

    const int TB = 256;
    const int gC = (int)(((long long)N * 128 / 4) / 256);   // 6250 (exact)
    const int NB = (N + 1023) / 1024;                       // 49
    const int G = NCH * NR;                                 // 448

    // ---- fused hist + prep ----
    {
        HPParams p;
        p.src = src; p.dst = dst; p.H = H; p.H2 = H2;
        p.E = E; p.NR = NR; p.NPAD = NPAD;
        p.x = x; p.xb = xb; p.gC = gC;
        p.W[0] = W1_0; p.WT[0] = W10T; p.K[0] = 128;
        p.W[1] = W1_1; p.WT[1] = W11T; p.K[1] = 128;
        p.W[2] = W2_0; p.WT[2] = W20T; p.K[2] = 256;
        p.W[3] = W2_1; p.WT[3] = W21T; p.K[3] = 256;
        p.W[4] = W3_0; p.WT[4] = W30T; p.K[4] = 256;
        p.W[5] = W3_1; p.WT[5] = W31T; p.K[5] = 256;
        hist_prep_kernel<<<2 * G + gC + 384, TB, 0, stream>>>(p);
    }

    // ---- CSR build ----
    reduce_scan_partial<<<NB, TB, 0, stream>>>(H, H2, cnt, dinv, part, N, NPAD);
    scan_small<<<1, 64, 0, stream>>>(part, NB, rowptr, N);
    scan_chunk_base<<<NB, TB, 0, stream>>>(cnt, part, H, rowptr, HS, N, NPAD);
    fill_kernel<<<G, TB, 0, stream>>>(src, dst, HS, esrc, E, NR, NPAD);

    dim3 gemmGrid((N + 31) / 32);
    dim3 gatherGrid((N + 7) / 8);

    // ---- layer 1: F=128 ----
    gather_bf16<128><<<gatherGrid, TB, 0, stream>>>(rowptr, esrc, dinv, xb, txb, N);
    gemm_mfma<128, true, u16><<<gemmGrid, TB, 0, stream>>>(xb, txb, W10T, W11T, b1, h1b, N);

    // ---- layer 2: F=256 ----
    gather_bf16<256><<<gatherGrid, TB, 0, stream>>>(rowptr, esrc, dinv, h1b, txb, N);
    gemm_mfma<256, true, u16><<<gemmGrid, TB, 0, stream>>>(h1b, txb, W20T, W21T, b2, h2b, N);

    // ---- layer 3: F=256, no relu, fp32 out ----
    gather_bf16<256><<<gatherGrid, TB, 0, stream>>>(rowptr, esrc, dinv, h2b, txb, N);
    gemm_mfma<256, false, float><<<gemmGrid, TB, 0, stream>>>(h2b, txb, W30T, W31T, b3, out, N);
}

// Round 11
// 363.778 us; speedup vs baseline: 1.0903x; 1.0016x over previous
//
#include <hip/hip_runtime.h>
#include <hip/hip_bf16.h>

// ---------------------------------------------------------------------------
// GraphChebNet: 3-layer ChebConv (K=2), N=50000, E=400000.
// Round 11: round-8 proven parts (ew-based x4-unrolled gather; 64x256 MFMA
// GEMM w/ swizzled global_load_lds) + round-10 counting-sort CSR (LDS-only
// atomics, NCH=64, zero memsets). fill restored to writing ew (self-loops
// excluded from H => absent from CSR, correct since their weight is 0).
// Round-10 regression attributed to 32-row GEMM (2x B staging) + dinv-lookup
// gather, both reverted here. 11 dispatches.
// ---------------------------------------------------------------------------

typedef __attribute__((ext_vector_type(8))) short bf16x8;
typedef __attribute__((ext_vector_type(4))) float f32x4;

#define NCH 64        // edge chunks
#define RBITS 13
#define RBINS 8192    // bins per range (32KB LDS as int)

__device__ __forceinline__ float bf2f(unsigned int lo16) {
    unsigned int t = lo16 << 16;
    return __builtin_bit_cast(float, t);
}
__device__ __forceinline__ unsigned short f2bf(float f) {
    unsigned int u = __builtin_bit_cast(unsigned int, f);
    unsigned int r = (u + 0x7fffu + ((u >> 16) & 1u)) >> 16;   // RNE
    return (unsigned short)r;
}

// ---------------- fused hist + prep ----------------
// blocks [0, G)        : dst histogram (s!=d) -> H   (CSR counts)
// blocks [G, 2G)       : src histogram (s!=d) -> H2  (deg)
// blocks [2G, 2G+gC)   : cast x -> bf16
// blocks [2G+gC, +384) : 6 weight transposes
struct HPParams {
    const int* src;
    const int* dst;
    int* H;
    int* H2;
    int E, NR, NPAD;
    const float* x;
    unsigned short* xb;
    int gC;
    const float* W[6];
    unsigned short* WT[6];
    int K[6];
};

__global__ __launch_bounds__(256) void hist_prep_kernel(HPParams p) {
    __shared__ int h[RBINS];
    int b = blockIdx.x;
    int tid = threadIdx.x;
    const int G = NCH * p.NR;

    if (b < 2 * G) {
        int srcpass = (b >= G);
        if (srcpass) b -= G;
        int c = b / p.NR, r = b % p.NR;
        int r0 = r << RBITS;
        for (int i = tid; i < RBINS; i += 256) h[i] = 0;
        __syncthreads();
        int EC = (p.E + NCH - 1) / NCH;
        int e0 = c * EC, e1 = min(e0 + EC, p.E);
        if (!srcpass) {
            for (int e = e0 + tid; e < e1; e += 256) {
                int d = p.dst[e];
                int dl = d - r0;
                if ((unsigned)dl < RBINS && p.src[e] != d) atomicAdd(&h[dl], 1);
            }
        } else {
            for (int e = e0 + tid; e < e1; e += 256) {
                int s = p.src[e];
                int sl = s - r0;
                if ((unsigned)sl < RBINS && s != p.dst[e]) atomicAdd(&h[sl], 1);
            }
        }
        __syncthreads();
        int* out = (srcpass ? p.H2 : p.H) + (size_t)c * p.NPAD + r0;
        for (int i = tid; i < RBINS; i += 256) out[i] = h[i];
        return;
    }
    b -= 2 * G;
    if (b < p.gC) {
        long long i = (long long)b * 256 + tid;   // exact: gC*256 elements
        float4 v = reinterpret_cast<const float4*>(p.x)[i];
        ushort4 o;
        o.x = f2bf(v.x); o.y = f2bf(v.y); o.z = f2bf(v.z); o.w = f2bf(v.w);
        reinterpret_cast<ushort4*>(p.xb)[i] = o;
        return;
    }
    b -= p.gC;                       // 0..383 : 6 matrices x 64 tiles
    float (*t)[33] = reinterpret_cast<float(*)[33]>(h);
    int m = b >> 6;
    int rem = b & 63;
    int K = p.K[m];
    int kb = (rem & 7) * 32, nb = (rem >> 3) * 32;
    if (kb >= K) return;
    const float* W = p.W[m];
    unsigned short* WT = p.WT[m];
    int lx = tid & 31, ly = tid >> 5;   // 32 x 8
    #pragma unroll
    for (int i = 0; i < 32; i += 8)
        t[ly + i][lx] = W[(size_t)(kb + ly + i) * 256 + nb + lx];
    __syncthreads();
    #pragma unroll
    for (int i = 0; i < 32; i += 8)
        WT[(size_t)(nb + ly + i) * K + kb + lx] = f2bf(t[lx][ly + i]);
}

// ---------------- reduce H/H2 -> cnt, dinv, scan partials ----------------
__global__ __launch_bounds__(256) void reduce_scan_partial(const int* __restrict__ H,
                                                           const int* __restrict__ H2,
                                                           int* __restrict__ cnt,
                                                           float* __restrict__ dinv,
                                                           int* __restrict__ part,
                                                           int N, int NPAD) {
    __shared__ int lds[256];
    int tid = threadIdx.x;
    int base = blockIdx.x * 1024 + tid * 4;
    int s = 0;
    #pragma unroll
    for (int i = 0; i < 4; ++i) {
        int d = base + i;
        if (d < N) {
            int cn = 0, dg = 0;
            for (int c = 0; c < NCH; ++c) {
                cn += H[(size_t)c * NPAD + d];
                dg += H2[(size_t)c * NPAD + d];
            }
            cnt[d] = cn;
            dinv[d] = (dg > 0) ? rsqrtf((float)dg) : 0.0f;
            s += cn;
        }
    }
    lds[tid] = s;
    __syncthreads();
    for (int off = 128; off > 0; off >>= 1) {
        if (tid < off) lds[tid] += lds[tid + off];
        __syncthreads();
    }
    if (tid == 0) part[blockIdx.x] = lds[0];
}

// wave-parallel exclusive scan of part[NB] (NB <= 64)
__global__ __launch_bounds__(64) void scan_small(int* __restrict__ part, int NB,
                                                 int* __restrict__ rowptr, int N) {
    int lane = threadIdx.x;
    int v = (lane < NB) ? part[lane] : 0;
    int inc = v;
    #pragma unroll
    for (int off = 1; off < 64; off <<= 1) {
        int t = __shfl_up(inc, off, 64);
        if (lane >= off) inc += t;
    }
    if (lane < NB) part[lane] = inc - v;   // exclusive
    if (lane == 63) rowptr[N] = inc;       // total
}

// rowptr (exclusive prefix of cnt) + per-chunk bases HS[c][d]
__global__ __launch_bounds__(256) void scan_chunk_base(const int* __restrict__ cnt,
                                                       const int* __restrict__ part,
                                                       const int* __restrict__ H,
                                                       int* __restrict__ rowptr,
                                                       int* __restrict__ HS,
                                                       int N, int NPAD) {
    __shared__ int lds[256];
    int tid = threadIdx.x;
    int base = blockIdx.x * 1024 + tid * 4;
    int c4[4];
    #pragma unroll
    for (int i = 0; i < 4; ++i) c4[i] = (base + i < N) ? cnt[base + i] : 0;
    int ts = c4[0] + c4[1] + c4[2] + c4[3];
    lds[tid] = ts;
    __syncthreads();
    for (int off = 1; off < 256; off <<= 1) {
        int v = (tid >= off) ? lds[tid - off] : 0;
        __syncthreads();
        lds[tid] += v;
        __syncthreads();
    }
    int o = part[blockIdx.x] + lds[tid] - ts;
    #pragma unroll
    for (int i = 0; i < 4; ++i) {
        int d = base + i;
        if (d < N) {
            rowptr[d] = o;
            int run = o;
            for (int c = 0; c < NCH; ++c) {
                HS[(size_t)c * NPAD + d] = run;
                run += H[(size_t)c * NPAD + d];
            }
            o = run;
        }
    }
}

// ---------------- fill: place non-self edges via LDS ranks, write ew --------
__global__ __launch_bounds__(256) void fill_kernel(const int* __restrict__ src,
                                                   const int* __restrict__ dst,
                                                   const float* __restrict__ dinv,
                                                   const int* __restrict__ HS,
                                                   int* __restrict__ esrc,
                                                   float* __restrict__ ew,
                                                   int E, int NR, int NPAD) {
    __shared__ int h[RBINS];
    int tid = threadIdx.x;
    int b = blockIdx.x;
    int c = b / NR, r = b % NR;
    int r0 = r << RBITS;
    for (int i = tid; i < RBINS; i += 256) h[i] = 0;
    __syncthreads();
    int EC = (E + NCH - 1) / NCH;
    int e0 = c * EC, e1 = min(e0 + EC, E);
    for (int e = e0 + tid; e < e1; e += 256) {
        int d = dst[e];
        int dl = d - r0;
        if ((unsigned)dl < RBINS) {
            int s = src[e];
            if (s != d) {
                int rank = atomicAdd(&h[dl], 1);
                int pos = HS[(size_t)c * NPAD + d] + rank;
                esrc[pos] = s;
                ew[pos] = -dinv[s] * dinv[d];
            }
        }
    }
}

// ---------------- gather (round-8): tx[n,:] = sum_e ew_e * x[src_e,:] -------
template <int V> struct RowT;
template <> struct RowT<4> { using T = uint2; };
template <> struct RowT<8> { using T = uint4; };

__device__ __forceinline__ void fma_row(float* acc, uint2 u, float wv) {
    acc[0] += wv * bf2f(u.x & 0xffffu);
    acc[1] += wv * bf2f(u.x >> 16);
    acc[2] += wv * bf2f(u.y & 0xffffu);
    acc[3] += wv * bf2f(u.y >> 16);
}
__device__ __forceinline__ void fma_row(float* acc, uint4 u, float wv) {
    acc[0] += wv * bf2f(u.x & 0xffffu);
    acc[1] += wv * bf2f(u.x >> 16);
    acc[2] += wv * bf2f(u.y & 0xffffu);
    acc[3] += wv * bf2f(u.y >> 16);
    acc[4] += wv * bf2f(u.z & 0xffffu);
    acc[5] += wv * bf2f(u.z >> 16);
    acc[6] += wv * bf2f(u.w & 0xffffu);
    acc[7] += wv * bf2f(u.w >> 16);
}
__device__ __forceinline__ void pack_out(unsigned short* q, const float* acc, uint2*) {
    uint2 o;
    o.x = (unsigned int)f2bf(acc[0]) | ((unsigned int)f2bf(acc[1]) << 16);
    o.y = (unsigned int)f2bf(acc[2]) | ((unsigned int)f2bf(acc[3]) << 16);
    *reinterpret_cast<uint2*>(q) = o;
}
__device__ __forceinline__ void pack_out(unsigned short* q, const float* acc, uint4*) {
    uint4 o;
    o.x = (unsigned int)f2bf(acc[0]) | ((unsigned int)f2bf(acc[1]) << 16);
    o.y = (unsigned int)f2bf(acc[2]) | ((unsigned int)f2bf(acc[3]) << 16);
    o.z = (unsigned int)f2bf(acc[4]) | ((unsigned int)f2bf(acc[5]) << 16);
    o.w = (unsigned int)f2bf(acc[6]) | ((unsigned int)f2bf(acc[7]) << 16);
    *reinterpret_cast<uint4*>(q) = o;
}

template <int F>
__global__ __launch_bounds__(256) void gather_bf16(const int* __restrict__ rowptr,
                                                   const int* __restrict__ esrc,
                                                   const float* __restrict__ ew,
                                                   const unsigned short* __restrict__ xb,
                                                   unsigned short* __restrict__ txb,
                                                   int N) {
    constexpr int V = F / 32;   // 4 (F=128) or 8 (F=256)
    using T = typename RowT<V>::T;
    int half = threadIdx.x >> 5;
    int lane = threadIdx.x & 31;
    int n = blockIdx.x * 8 + half;
    if (n >= N) return;
    int beg = rowptr[n], end = rowptr[n + 1];
    float acc[V] = {};

    int k = beg;
    for (; k + 4 <= end; k += 4) {
        int s0 = esrc[k], s1 = esrc[k + 1], s2 = esrc[k + 2], s3 = esrc[k + 3];
        float w0 = ew[k], w1 = ew[k + 1], w2 = ew[k + 2], w3 = ew[k + 3];
        T r0 = *reinterpret_cast<const T*>(&xb[(size_t)s0 * F + lane * V]);
        T r1 = *reinterpret_cast<const T*>(&xb[(size_t)s1 * F + lane * V]);
        T r2 = *reinterpret_cast<const T*>(&xb[(size_t)s2 * F + lane * V]);
        T r3 = *reinterpret_cast<const T*>(&xb[(size_t)s3 * F + lane * V]);
        fma_row(acc, r0, w0);
        fma_row(acc, r1, w1);
        fma_row(acc, r2, w2);
        fma_row(acc, r3, w3);
    }
    for (; k < end; ++k) {
        int s = esrc[k];
        float wv = ew[k];
        T r = *reinterpret_cast<const T*>(&xb[(size_t)s * F + lane * V]);
        fma_row(acc, r, wv);
    }

    pack_out(&txb[(size_t)n * F + lane * V], acc, (T*)nullptr);
}

// ---------------- MFMA GEMM (round-8): 64x256, global_load_lds staging ------
template <int K, bool RELU, typename OutT>
__global__ __launch_bounds__(256, 3) void gemm_mfma(const unsigned short* __restrict__ Xb,
                                                    const unsigned short* __restrict__ Tb,
                                                    const unsigned short* __restrict__ W0T,
                                                    const unsigned short* __restrict__ W1T,
                                                    const float* __restrict__ bias,
                                                    OutT* __restrict__ out, int M) {
    __shared__ unsigned short As[64 * 64];
    __shared__ unsigned short Bs[256 * 64];

    const int tid = threadIdx.x;
    const int wave = tid >> 6;
    const int lane = tid & 63;
    const int l15 = lane & 15;
    const int quad = lane >> 4;
    const int row0 = blockIdx.x * 64;
    const int swz = ((lane & 7) ^ ((lane >> 3) & 7)) * 8;   // shorts

    f32x4 acc[4][4];
    #pragma unroll
    for (int i = 0; i < 4; ++i)
        #pragma unroll
        for (int j = 0; j < 4; ++j) acc[i][j] = (f32x4){0.f, 0.f, 0.f, 0.f};

    typedef const __attribute__((address_space(1))) void gvoid;
    typedef __attribute__((address_space(3))) void lvoid;

    #pragma unroll
    for (int pass = 0; pass < 2; ++pass) {
        const unsigned short* Amat = pass ? Tb : Xb;
        const unsigned short* Wmat = pass ? W1T : W0T;
        for (int k0 = 0; k0 < K; k0 += 64) {
            if (pass != 0 || k0 != 0) __syncthreads();
            #pragma unroll
            for (int r = 0; r < 2; ++r) {
                int grow = row0 + r * 32 + wave * 8 + (lane >> 3);
                if (grow > M - 1) grow = M - 1;
                const unsigned short* gp = &Amat[(size_t)grow * K + k0 + swz];
                __builtin_amdgcn_global_load_lds((gvoid*)gp,
                    (lvoid*)&As[(r * 32 + wave * 8) * 64], 16, 0, 0);
            }
            #pragma unroll
            for (int r = 0; r < 8; ++r) {
                int brow = r * 32 + wave * 8 + (lane >> 3);
                const unsigned short* gp = &Wmat[(size_t)brow * K + k0 + swz];
                __builtin_amdgcn_global_load_lds((gvoid*)gp,
                    (lvoid*)&Bs[(r * 32 + wave * 8) * 64], 16, 0, 0);
            }
            __syncthreads();

            #pragma unroll
            for (int kf = 0; kf < 2; ++kf) {
                const int col = (((kf * 4 + quad) ^ (l15 & 7)) * 8);
                bf16x8 a[4], b[4];
                #pragma unroll
                for (int mt = 0; mt < 4; ++mt)
                    a[mt] = *reinterpret_cast<const bf16x8*>(&As[(mt * 16 + l15) * 64 + col]);
                #pragma unroll
                for (int nt = 0; nt < 4; ++nt)
                    b[nt] = *reinterpret_cast<const bf16x8*>(
                        &Bs[(wave * 64 + nt * 16 + l15) * 64 + col]);
                #pragma unroll
                for (int mt = 0; mt < 4; ++mt)
                    #pragma unroll
                    for (int nt = 0; nt < 4; ++nt)
                        acc[mt][nt] = __builtin_amdgcn_mfma_f32_16x16x32_bf16(
                            a[mt], b[nt], acc[mt][nt], 0, 0, 0);
            }
        }
    }

    // epilogue: C/D layout col=lane&15, row=quad*4+reg
    #pragma unroll
    for (int mt = 0; mt < 4; ++mt) {
        #pragma unroll
        for (int r = 0; r < 4; ++r) {
            int m = row0 + mt * 16 + quad * 4 + r;
            if (m >= M) continue;
            #pragma unroll
            for (int nt = 0; nt < 4; ++nt) {
                int n = wave * 64 + nt * 16 + l15;
                float v = acc[mt][nt][r] + bias[n];
                if (RELU) v = fmaxf(v, 0.0f);
                if constexpr (sizeof(OutT) == 2)
                    out[(size_t)m * 256 + n] = (OutT)f2bf(v);
                else
                    out[(size_t)m * 256 + n] = (OutT)v;
            }
        }
    }
}

static inline size_t align_up(size_t v, size_t a) { return (v + a - 1) / a * a; }

extern "C" void kernel_launch(void* const* d_in, const int* in_sizes, int n_in,
                              void* d_out, int out_size, void* d_ws, size_t ws_size,
                              hipStream_t stream) {
    const float* x    = (const float*)d_in[0];
    const int*   ei   = (const int*)d_in[1];
    const float* W1_0 = (const float*)d_in[2];
    const float* W1_1 = (const float*)d_in[3];
    const float* b1   = (const float*)d_in[4];
    const float* W2_0 = (const float*)d_in[5];
    const float* W2_1 = (const float*)d_in[6];
    const float* b2   = (const float*)d_in[7];
    const float* W3_0 = (const float*)d_in[8];
    const float* W3_1 = (const float*)d_in[9];
    const float* b3   = (const float*)d_in[10];
    float* out = (float*)d_out;

    const int N = in_sizes[0] / 128;
    const int E = in_sizes[1] / 2;
    const int* src = ei;
    const int* dst = ei + E;

    const int NR = (N + RBINS - 1) / RBINS;     // 7 for N=50000
    const int NPAD = NR * RBINS;                // 57344

    typedef unsigned short u16;
    char* ws = (char*)d_ws;
    size_t off = 0;
    float* dinv   = (float*)(ws + off); off = align_up(off + (size_t)N * 4, 256);
    int*   cnt    = (int*)  (ws + off); off = align_up(off + (size_t)N * 4, 256);
    int*   rowptr = (int*)  (ws + off); off = align_up(off + (size_t)(N + 1) * 4, 256);
    int*   part   = (int*)  (ws + off); off = align_up(off + 256 * 4, 256);
    int*   H      = (int*)  (ws + off); off = align_up(off + (size_t)NCH * NPAD * 4, 256);
    int*   H2     = (int*)  (ws + off); off = align_up(off + (size_t)NCH * NPAD * 4, 256);
    int*   HS     = (int*)  (ws + off); off = align_up(off + (size_t)NCH * NPAD * 4, 256);
    int*   esrc   = (int*)  (ws + off); off = align_up(off + (size_t)E * 4, 256);
    float* ew     = (float*)(ws + off); off = align_up(off + (size_t)E * 4, 256);
    u16*   xb     = (u16*)  (ws + off); off = align_up(off + (size_t)N * 128 * 2, 256);
    u16*   txb    = (u16*)  (ws + off); off = align_up(off + (size_t)N * 256 * 2, 256);
    u16*   h1b    = (u16*)  (ws + off); off = align_up(off + (size_t)N * 256 * 2, 256);
    u16*   h2b    = (u16*)  (ws + off); off = align_up(off + (size_t)N * 256 * 2, 256);
    u16*   W10T   = (u16*)  (ws + off); off = align_up(off + (size_t)256 * 128 * 2, 256);
    u16*   W11T   = (u16*)  (ws + off); off = align_up(off + (size_t)256 * 128 * 2, 256);
    u16*   W20T   = (u16*)  (ws + off); off = align_up(off + (size_t)256 * 256 * 2, 256);
    u16*   W21T   = (u16*)  (ws + off); off = align_up(off + (size_t)256 * 256 * 2, 256);
    u16*   W30T   = (u16*)  (ws + off); off = align_up(off + (size_t)256 * 256 * 2, 256);
    u16*   W31T   = (u16*)  (ws + off); off = align_up(off + (size_t)256 * 256 * 2, 256);
    (void)ws_size;

    const int TB = 256;
    const int gC = (int)(((long long)N * 128 / 4) / 256);   // 6250 (exact)
    const int NB = (N + 1023) / 1024;                       // 49
    const int G = NCH * NR;                                 // 448

    // ---- fused hist + prep (LDS atomics only, no memsets) ----
    {
        HPParams p;
        p.src = src; p.dst = dst; p.H = H; p.H2 = H2;
        p.E = E; p.NR = NR; p.NPAD = NPAD;
        p.x = x; p.xb = xb; p.gC = gC;
        p.W[0] = W1_0; p.WT[0] = W10T; p.K[0] = 128;
        p.W[1] = W1_1; p.WT[1] = W11T; p.K[1] = 128;
        p.W[2] = W2_0; p.WT[2] = W20T; p.K[2] = 256;
        p.W[3] = W2_1; p.WT[3] = W21T; p.K[3] = 256;
        p.W[4] = W3_0; p.WT[4] = W30T; p.K[4] = 256;
        p.W[5] = W3_1; p.WT[5] = W31T; p.K[5] = 256;
        hist_prep_kernel<<<2 * G + gC + 384, TB, 0, stream>>>(p);
    }

    // ---- CSR build ----
    reduce_scan_partial<<<NB, TB, 0, stream>>>(H, H2, cnt, dinv, part, N, NPAD);
    scan_small<<<1, 64, 0, stream>>>(part, NB, rowptr, N);
    scan_chunk_base<<<NB, TB, 0, stream>>>(cnt, part, H, rowptr, HS, N, NPAD);
    fill_kernel<<<G, TB, 0, stream>>>(src, dst, dinv, HS, esrc, ew, E, NR, NPAD);

    dim3 gemmGrid((N + 63) / 64);
    dim3 gatherGrid((N + 7) / 8);

    // ---- layer 1: F=128 ----
    gather_bf16<128><<<gatherGrid, TB, 0, stream>>>(rowptr, esrc, ew, xb, txb, N);
    gemm_mfma<128, true, u16><<<gemmGrid, TB, 0, stream>>>(xb, txb, W10T, W11T, b1, h1b, N);

    // ---- layer 2: F=256 ----
    gather_bf16<256><<<gatherGrid, TB, 0, stream>>>(rowptr, esrc, ew, h1b, txb, N);
    gemm_mfma<256, true, u16><<<gemmGrid, TB, 0, stream>>>(h1b, txb, W20T, W21T, b2, h2b, N);

    // ---- layer 3: F=256, no relu, fp32 out ----
    gather_bf16<256><<<gatherGrid, TB, 0, stream>>>(rowptr, esrc, ew, h2b, txb, N);
    gemm_mfma<256, false, float><<<gemmGrid, TB, 0, stream>>>(h2b, txb, W30T, W31T, b3, out, N);
}